// Round 1
// baseline (180.387 us; speedup 1.0000x reference)
//
#include <hip/hip_runtime.h>

#define HF 400
#define WF 400
#define NB 8
#define ND 96
#define NH 192
#define NW 192

// out[b,d,h,w] = bilinear(fluence[b], iy(d,h), ix(d,w)) * pc[d]
// grid layout: sampling_grids[D, W, H, 2]; x = [...,0] depends only on (d,w),
// y = [...,1] depends only on (d,h) (outer-product structure of the grid).
__global__ __launch_bounds__(NW) void fluence_vol_kernel(
    const float* __restrict__ fluence,   // [B, HF, WF]
    const float* __restrict__ grids,     // [D, W, H, 2]
    const float* __restrict__ pc,        // [D]
    float* __restrict__ out)             // [B, D, H, W]
{
    const int w = threadIdx.x;
    const int h = blockIdx.x;
    const int d = blockIdx.y;

    // x at [d, w, 0, 0]; y at [d, 0, h, 1]
    const float x = grids[((size_t)(d * NW + w) * NH) * 2 + 0];
    const float y = grids[((size_t)d * NW * NH + h) * 2 + 1];

    const float ix = ((x + 1.0f) * WF - 1.0f) * 0.5f;
    const float iy = ((y + 1.0f) * HF - 1.0f) * 0.5f;
    const float ix0f = floorf(ix);
    const float iy0f = floorf(iy);
    const float wx1 = ix - ix0f;
    const float wy1 = iy - iy0f;
    const float wx0 = 1.0f - wx1;
    const float wy0 = 1.0f - wy1;

    const int ix0 = (int)ix0f, iy0 = (int)iy0f;
    const int ix1 = ix0 + 1,   iy1 = iy0 + 1;

    const bool vx0 = (ix0 >= 0) & (ix0 < WF);
    const bool vx1 = (ix1 >= 0) & (ix1 < WF);
    const bool vy0 = (iy0 >= 0) & (iy0 < HF);
    const bool vy1 = (iy1 >= 0) & (iy1 < HF);

    const int cx0 = min(max(ix0, 0), WF - 1);
    const int cx1 = min(max(ix1, 0), WF - 1);
    const int cy0 = min(max(iy0, 0), HF - 1);
    const int cy1 = min(max(iy1, 0), HF - 1);

    const float w00 = (vy0 & vx0) ? (wy0 * wx0) : 0.0f;
    const float w01 = (vy0 & vx1) ? (wy0 * wx1) : 0.0f;
    const float w10 = (vy1 & vx0) ? (wy1 * wx0) : 0.0f;
    const float w11 = (vy1 & vx1) ? (wy1 * wx1) : 0.0f;

    const float corr = pc[d];

    const int r0 = cy0 * WF;
    const int r1 = cy1 * WF;

#pragma unroll
    for (int b = 0; b < NB; ++b) {
        const float* __restrict__ img = fluence + (size_t)b * (HF * WF);
        const float v = img[r0 + cx0] * w00 + img[r0 + cx1] * w01 +
                        img[r1 + cx0] * w10 + img[r1 + cx1] * w11;
        out[(((size_t)b * ND + d) * NH + h) * NW + w] = v * corr;
    }
}

extern "C" void kernel_launch(void* const* d_in, const int* in_sizes, int n_in,
                              void* d_out, int out_size, void* d_ws, size_t ws_size,
                              hipStream_t stream) {
    const float* fluence = (const float*)d_in[0];  // [8, 400, 400]
    const float* grids   = (const float*)d_in[1];  // [96, 192, 192, 2]
    const float* pc      = (const float*)d_in[2];  // [96]
    float* out = (float*)d_out;                    // [8, 96, 192, 192]

    dim3 grid(NH, ND);   // (h, d)
    dim3 block(NW);      // w
    fluence_vol_kernel<<<grid, block, 0, stream>>>(fluence, grids, pc, out);
}

// Round 2
// 177.927 us; speedup vs baseline: 1.0138x; 1.0138x over previous
//
#include <hip/hip_runtime.h>

#define HF 400
#define WF 400
#define NB 8
#define ND 96
#define NH 192
#define NW 192

// Block = (d,h): all threads share source rows cy0/cy1 (y depends only on d,h).
// Stage those rows for all 8 batches into LDS with coalesced float4 loads,
// then gather the 4 bilinear corners from LDS.
__global__ __launch_bounds__(NW) void fluence_vol_kernel(
    const float* __restrict__ fluence,   // [B, HF, WF]
    const float* __restrict__ grids,     // [D, W, H, 2]
    const float* __restrict__ pc,        // [D]
    float* __restrict__ out)             // [B, D, H, W]
{
    __shared__ float lds[NB * 2 * WF];   // [b][rr][x] = 25.6 KB

    const int w = threadIdx.x;
    const int h = blockIdx.x;
    const int d = blockIdx.y;

    // ---- block-uniform y path ----
    const float y = grids[((size_t)d * NW * NH + h) * 2 + 1];
    const float iy = ((y + 1.0f) * HF - 1.0f) * 0.5f;
    const float iy0f = floorf(iy);
    const int iy0 = (int)iy0f;
    const int iy1 = iy0 + 1;
    const float wy1 = iy - iy0f;
    const float wy0 = 1.0f - wy1;
    const int cy0 = min(max(iy0, 0), HF - 1);
    const int cy1 = min(max(iy1, 0), HF - 1);
    const float wyv0 = ((iy0 >= 0) & (iy0 < HF)) ? wy0 : 0.0f;
    const float wyv1 = ((iy1 >= 0) & (iy1 < HF)) ? wy1 : 0.0f;

    // ---- stage 16 rows (8 batches x 2 rows) of 400 floats as float4 ----
    // 16 rows * 100 float4 = 1600 float4 total
    for (int j = threadIdx.x; j < NB * 2 * 100; j += NW) {
        const int row = j / 100;          // 0..15
        const int c4  = j - row * 100;    // 0..99
        const int b   = row >> 1;
        const int rr  = row & 1;
        const int src_row = rr ? cy1 : cy0;
        const float4 v = *(const float4*)(fluence + ((size_t)b * HF + src_row) * WF + c4 * 4);
        *(float4*)(lds + (size_t)(b * 2 + rr) * WF + c4 * 4) = v;
    }
    __syncthreads();

    // ---- per-thread x path ----
    const float x = grids[((size_t)(d * NW + w) * NH) * 2 + 0];
    const float ix = ((x + 1.0f) * WF - 1.0f) * 0.5f;
    const float ix0f = floorf(ix);
    const int ix0 = (int)ix0f;
    const int ix1 = ix0 + 1;
    const float wx1 = ix - ix0f;
    const float wx0 = 1.0f - wx1;
    const int cx0 = min(max(ix0, 0), WF - 1);
    const int cx1 = min(max(ix1, 0), WF - 1);
    const float wxv0 = ((ix0 >= 0) & (ix0 < WF)) ? wx0 : 0.0f;
    const float wxv1 = ((ix1 >= 0) & (ix1 < WF)) ? wx1 : 0.0f;

    const float w00 = wyv0 * wxv0;
    const float w01 = wyv0 * wxv1;
    const float w10 = wyv1 * wxv0;
    const float w11 = wyv1 * wxv1;

    const float corr = pc[d];

#pragma unroll
    for (int b = 0; b < NB; ++b) {
        const float* __restrict__ L = lds + b * (2 * WF);
        const float v = L[cx0] * w00 + L[cx1] * w01 +
                        L[WF + cx0] * w10 + L[WF + cx1] * w11;
        out[(((size_t)b * ND + d) * NH + h) * NW + w] = v * corr;
    }
}

extern "C" void kernel_launch(void* const* d_in, const int* in_sizes, int n_in,
                              void* d_out, int out_size, void* d_ws, size_t ws_size,
                              hipStream_t stream) {
    const float* fluence = (const float*)d_in[0];  // [8, 400, 400]
    const float* grids   = (const float*)d_in[1];  // [96, 192, 192, 2]
    const float* pc      = (const float*)d_in[2];  // [96]
    float* out = (float*)d_out;                    // [8, 96, 192, 192]

    dim3 grid(NH, ND);   // (h, d)
    dim3 block(NW);      // w
    fluence_vol_kernel<<<grid, block, 0, stream>>>(fluence, grids, pc, out);
}

// Round 3
// 153.936 us; speedup vs baseline: 1.1718x; 1.1559x over previous
//
#include <hip/hip_runtime.h>

#define HF 400
#define WF 400
#define NB 8
#define ND 96
#define NH 192
#define NW 192
#define TH 8   // h-values per thread: amortizes x-setup, one occupancy round

// Thread owns (d,w), loops TH h-values. Corners cx0,cx0+1 fetched as ONE
// float2 with pre-folded pair weights (ax,bx). No LDS, no barrier.
__global__ __launch_bounds__(NW) void fluence_vol_kernel(
    const float* __restrict__ fluence,   // [B, HF, WF]
    const float* __restrict__ grids,     // [D, W, H, 2]
    const float* __restrict__ pc,        // [D]
    float* __restrict__ out)             // [B, D, H, W]
{
    const int w  = threadIdx.x;
    const int h0 = blockIdx.x * TH;
    const int d  = blockIdx.y;

    // ---- per-thread x path (once per 8*TH outputs) ----
    const float x = grids[(d * NW + w) * NH * 2];
    const float ix = ((x + 1.0f) * WF - 1.0f) * 0.5f;
    const float ix0f = floorf(ix);
    const int ix0 = (int)ix0f;
    const int ix1 = ix0 + 1;
    const float wx1 = ix - ix0f;
    const float wx0 = 1.0f - wx1;
    const int cx0 = min(max(ix0, 0), WF - 1);
    const int cx1 = min(max(ix1, 0), WF - 1);
    const int xb  = min(max(ix0, 0), WF - 2);   // pair window [xb, xb+1], always in-row
    const float wxv0 = ((ix0 >= 0) && (ix0 < WF)) ? wx0 : 0.0f;
    const float wxv1 = ((ix1 >= 0) && (ix1 < WF)) ? wx1 : 0.0f;
    // fold corner->pair-element selection into two weights
    const float ax = ((cx0 == xb)     ? wxv0 : 0.0f) + ((cx1 == xb)     ? wxv1 : 0.0f);
    const float bx = ((cx0 == xb + 1) ? wxv0 : 0.0f) + ((cx1 == xb + 1) ? wxv1 : 0.0f);

    const float corr = pc[d];
    const float* __restrict__ gy = grids + (d * NW * NH) * 2 + 1;

#pragma unroll
    for (int hh = 0; hh < TH; ++hh) {
        const int h = h0 + hh;
        // ---- block-uniform y path ----
        const float y = gy[h * 2];
        const float iy = ((y + 1.0f) * HF - 1.0f) * 0.5f;
        const float iy0f = floorf(iy);
        const int iy0 = (int)iy0f;
        const int iy1 = iy0 + 1;
        const float wy1 = iy - iy0f;
        const float wy0 = 1.0f - wy1;
        const int cy0 = min(max(iy0, 0), HF - 1);
        const int cy1 = min(max(iy1, 0), HF - 1);
        const float wyc0 = (((iy0 >= 0) && (iy0 < HF)) ? wy0 : 0.0f) * corr;
        const float wyc1 = (((iy1 >= 0) && (iy1 < HF)) ? wy1 : 0.0f) * corr;

        const int r0 = cy0 * WF + xb;
        const int r1 = cy1 * WF + xb;

        float2 p0[NB], p1[NB];
#pragma unroll
        for (int b = 0; b < NB; ++b) {
            const float* __restrict__ img = fluence + b * (HF * WF);
            p0[b] = *(const float2*)(img + r0);   // corners (cy0, xb), (cy0, xb+1)
            p1[b] = *(const float2*)(img + r1);   // corners (cy1, xb), (cy1, xb+1)
        }
#pragma unroll
        for (int b = 0; b < NB; ++b) {
            const float v0 = fmaf(p0[b].y, bx, p0[b].x * ax);
            const float v1 = fmaf(p1[b].y, bx, p1[b].x * ax);
            out[((b * ND + d) * NH + h) * NW + w] = fmaf(v1, wyc1, v0 * wyc0);
        }
    }
}

extern "C" void kernel_launch(void* const* d_in, const int* in_sizes, int n_in,
                              void* d_out, int out_size, void* d_ws, size_t ws_size,
                              hipStream_t stream) {
    const float* fluence = (const float*)d_in[0];  // [8, 400, 400]
    const float* grids   = (const float*)d_in[1];  // [96, 192, 192, 2]
    const float* pc      = (const float*)d_in[2];  // [96]
    float* out = (float*)d_out;                    // [8, 96, 192, 192]

    dim3 grid(NH / TH, ND);   // (h-tile, d)
    dim3 block(NW);           // w
    fluence_vol_kernel<<<grid, block, 0, stream>>>(fluence, grids, pc, out);
}